// Round 1
// baseline (245.458 us; speedup 1.0000x reference)
//
#include <hip/hip_runtime.h>
#include <hip/hip_bf16.h>

#define EPSF 1e-8f
#define GAINF 0.014731391274719739f   // 1/sqrt(512*9)

typedef __attribute__((ext_vector_type(8))) __bf16 bf16x8;
typedef __attribute__((ext_vector_type(16))) float f32x16;

// ---------------- K1a: weight -> bf16 [t][o][i], plus S[o,i] = sum_t w^2 ----
__global__ void k_prep_w(const float* __restrict__ w, float* __restrict__ S,
                         __hip_bfloat16* __restrict__ wbf) {
  int idx = blockIdx.x * 256 + threadIdx.x;  // o*512 + i, total 262144
  const float* p = w + idx * 9;
  float s = 0.f;
#pragma unroll
  for (int t = 0; t < 9; ++t) {
    float v = p[t];
    s += v * v;
    wbf[t * (512 * 512) + idx] = __float2bfloat16(v);
  }
  S[idx] = s;
}

// ---------------- K1b: esc[b,o] = GAIN * rsqrt(GAIN^2 * sum_i style^2 * S + eps)
__global__ void k_sigma(const float* __restrict__ style, const float* __restrict__ S,
                        float* __restrict__ esc) {
  int gid = blockIdx.x * 4 + (threadIdx.x >> 6);  // one wave per (b,o), 8192 total
  int lane = threadIdx.x & 63;
  int b = gid >> 9, o = gid & 511;
  float s = 0.f;
#pragma unroll
  for (int j = 0; j < 8; ++j) {
    float st = style[b * 512 + j * 64 + lane];
    s += st * st * S[o * 512 + j * 64 + lane];
  }
#pragma unroll
  for (int off = 32; off; off >>= 1) s += __shfl_down(s, off);
  if (lane == 0) esc[gid] = GAINF * rsqrtf(s * (GAINF * GAINF) + EPSF);
}

// ---------------- K2z: zero the padded border of xs_pad[b][34][34][512] ------
__global__ void k_zero_border(__hip_bfloat16* __restrict__ xs) {
  int ch = blockIdx.x * 256 + threadIdx.x;  // 0..511
  int s = blockIdx.y;                       // 0..131 border sites
  int b = blockIdx.z;
  int yp, xp;
  if (s < 34) { yp = 0; xp = s; }
  else if (s < 68) { yp = 33; xp = s - 34; }
  else { int t2 = s - 68; yp = 1 + (t2 >> 1); xp = (t2 & 1) * 33; }
  xs[(((b * 34) + yp) * 34 + xp) * 512 + ch] = __float2bfloat16(0.f);
}

// ---------------- K2: xs_pad[b][y+1][x+1][i] = bf16(style[b,i] * x[b,i,y,x]) -
// LDS transpose: coalesced read (pixel-inner) AND coalesced write (channel-inner)
__global__ void k_pack_x(const float* __restrict__ x, const float* __restrict__ style,
                         __hip_bfloat16* __restrict__ xs) {
  __shared__ float tile[64][65];
  int b = blockIdx.z, pt = blockIdx.y, ct = blockIdx.x;
  int p0 = pt * 64, c0 = ct * 64;
  int tx = threadIdx.x & 63, ty = threadIdx.x >> 6;
#pragma unroll
  for (int k = 0; k < 16; ++k) {
    int ci = ty + k * 4;
    tile[ci][tx] = x[((b * 512) + (c0 + ci)) * 1024 + p0 + tx];
  }
  __syncthreads();
  float st = style[b * 512 + c0 + tx];  // this thread writes channel c0+tx
#pragma unroll
  for (int k = 0; k < 16; ++k) {
    int pi = ty + k * 4;
    int p = p0 + pi;
    int y = p >> 5, xx = p & 31;
    xs[(((b * 34) + (y + 1)) * 34 + (xx + 1)) * 512 + (c0 + tx)] =
        __float2bfloat16(tile[tx][pi] * st);
  }
}

// ---------------- K3: implicit-GEMM conv, 32x32x16 bf16 MFMA -----------------
// Tile: BM=128 (out ch) x BN=256 (pixels = 8 rows of one image). grid=256, 1 blk/CU.
// B-tile staged once per 32-ch K-step; all 9 taps read shifted views from LDS.
__global__ __launch_bounds__(512, 2) void k_conv(
    const __hip_bfloat16* __restrict__ wbf, const __hip_bfloat16* __restrict__ xs,
    const float* __restrict__ esc, float* __restrict__ out) {
  // 340 sites (10 padded rows x 34 cols) x 32 ch, chunk-XOR-swizzled
  __shared__ __hip_bfloat16 ldsB[340 * 32];
  int g = blockIdx.x;
  // XCD swizzle: same-n m-pairs co-resident per XCD; A slice (2.36MB) L2-resident
  int xcd = g & 7, sblk = g >> 3;
  int m = ((xcd & 1) << 1) | (sblk & 1);          // 0..3 m-tile
  int n = ((xcd >> 1) << 4) | (sblk >> 1);        // 0..63 n-tile
  int b = n >> 2, nt = n & 3;
  int row0 = nt << 3;                             // image row base (8 rows/tile)
  int tid = threadIdx.x;
  int lane = tid & 63, wave = tid >> 6;
  int wm = wave >> 2, wn = wave & 3;              // wave grid 2m x 4n, each 64x64
  int l31 = lane & 31, lhi = lane >> 5;
  int obase = (m << 7) + (wm << 6);
  int pbase = wn << 6;

  f32x16 acc[2][2];
#pragma unroll
  for (int i = 0; i < 2; ++i)
#pragma unroll
    for (int j = 0; j < 2; ++j)
#pragma unroll
      for (int e = 0; e < 16; ++e) acc[i][j][e] = 0.f;

  const __hip_bfloat16* xbase = xs + ((b * 34 + row0) * 34) * 512;

  for (int cb = 0; cb < 16; ++cb) {
    // ---- stage B: 1360 16B chunks (340 sites x 4), swizzle q ^= (site>>1)&3
    for (int idx = tid; idx < 1360; idx += 512) {
      int st = idx >> 2, q0 = idx & 3;
      int r = (st * 241) >> 13;        // st / 34, exact for st in [0,339]
      int c = st - r * 34;
      int qs = q0 ^ ((st >> 1) & 3);
      bf16x8 v = *reinterpret_cast<const bf16x8*>(
          xbase + ((r * 34 + c) << 9) + (cb << 5) + (qs << 3));
      *reinterpret_cast<bf16x8*>(&ldsB[idx * 8]) = v;
    }
    __syncthreads();
    const __hip_bfloat16* wb = wbf + (cb << 5);
#pragma unroll
    for (int t = 0; t < 9; ++t) {
      const int dy = t / 3, dx = t % 3;
#pragma unroll
      for (int k = 0; k < 2; ++k) {    // two K=16 steps cover the 32-ch block
        // A frags straight from global (L1/L2-cached, reused x128 pixels)
        bf16x8 a0 = *reinterpret_cast<const bf16x8*>(
            wb + t * (512 * 512) + (obase + l31) * 512 + (k << 4) + (lhi << 3));
        bf16x8 a1 = *reinterpret_cast<const bf16x8*>(
            wb + t * (512 * 512) + (obase + 32 + l31) * 512 + (k << 4) + (lhi << 3));
        int ko = (k << 1) | lhi;
        int s0 = ((pbase >> 5) + dy) * 34 + l31 + dx;  // nsub=0 site
        int s1 = s0 + 34;                              // nsub=1 (next pixel row)
        int c0i = (s0 << 2) + (ko ^ ((s0 >> 1) & 3));
        int c1i = (s1 << 2) + (ko ^ ((s1 >> 1) & 3));
        bf16x8 b0 = *reinterpret_cast<const bf16x8*>(&ldsB[c0i * 8]);
        bf16x8 b1 = *reinterpret_cast<const bf16x8*>(&ldsB[c1i * 8]);
        acc[0][0] = __builtin_amdgcn_mfma_f32_32x32x16_bf16(a0, b0, acc[0][0], 0, 0, 0);
        acc[0][1] = __builtin_amdgcn_mfma_f32_32x32x16_bf16(a0, b1, acc[0][1], 0, 0, 0);
        acc[1][0] = __builtin_amdgcn_mfma_f32_32x32x16_bf16(a1, b0, acc[1][0], 0, 0, 0);
        acc[1][1] = __builtin_amdgcn_mfma_f32_32x32x16_bf16(a1, b1, acc[1][1], 0, 0, 0);
      }
    }
    __syncthreads();
  }
  // ---- epilogue: C/D layout col=lane&31, row=(reg&3)+8*(reg>>2)+4*(lane>>5)
  int outbase = (b << 19) + (nt << 8);
#pragma unroll
  for (int ms = 0; ms < 2; ++ms)
#pragma unroll
    for (int reg = 0; reg < 16; ++reg) {
      int o = obase + ms * 32 + (reg & 3) + ((reg >> 2) << 3) + (lhi << 2);
      float e = esc[(b << 9) + o];
#pragma unroll
      for (int ns = 0; ns < 2; ++ns) {
        int p = pbase + ns * 32 + l31;
        out[outbase + (o << 10) + p] = acc[ms][ns][reg] * e;
      }
    }
}

extern "C" void kernel_launch(void* const* d_in, const int* in_sizes, int n_in,
                              void* d_out, int out_size, void* d_ws, size_t ws_size,
                              hipStream_t stream) {
  const float* x = (const float*)d_in[0];      // [16,512,32,32]
  const float* style = (const float*)d_in[1];  // [16,512]
  const float* w = (const float*)d_in[2];      // [512,512,3,3]
  float* out = (float*)d_out;                  // [16,512,32,32]
  char* ws = (char*)d_ws;
  // workspace layout (24.74 MB total)
  __hip_bfloat16* wbf = (__hip_bfloat16*)(ws);              // 9*512*512*2 = 4,718,592
  __hip_bfloat16* xs  = (__hip_bfloat16*)(ws + 4718592);    // 16*34*34*512*2 = 18,939,904
  float* S   = (float*)(ws + 23658496);                     // 512*512*4
  float* esc = (float*)(ws + 24707072);                     // 8192*4

  hipLaunchKernelGGL(k_prep_w, dim3(1024), dim3(256), 0, stream, w, S, wbf);
  hipLaunchKernelGGL(k_sigma, dim3(2048), dim3(256), 0, stream, style, S, esc);
  hipLaunchKernelGGL(k_zero_border, dim3(2, 132, 16), dim3(256), 0, stream, xs);
  hipLaunchKernelGGL(k_pack_x, dim3(8, 16, 16), dim3(256), 0, stream, x, style, xs);
  hipLaunchKernelGGL(k_conv, dim3(256), dim3(512), 0, stream, wbf, xs, esc, out);
}

// Round 2
// 236.430 us; speedup vs baseline: 1.0382x; 1.0382x over previous
//
#include <hip/hip_runtime.h>
#include <hip/hip_bf16.h>

#define EPSF 1e-8f
#define GAINF 0.014731391274719739f   // 1/sqrt(512*9)

typedef __attribute__((ext_vector_type(8))) __bf16 bf16x8;
typedef __attribute__((ext_vector_type(16))) float f32x16;

// async 16B global -> LDS (DMA). LDS dest = wave-uniform base + lane*16;
// the bank swizzle is applied on the per-lane GLOBAL address instead.
#define GLOAD_LDS16(gp, lp) __builtin_amdgcn_global_load_lds( \
    (const __attribute__((address_space(1))) unsigned int*)(gp), \
    (__attribute__((address_space(3))) unsigned int*)(lp), 16, 0, 0)

// ---------------- K1 (fused): pack_x + prep_w + border zero ------------------
__global__ void k_prep(const float* __restrict__ x, const float* __restrict__ style,
                       const float* __restrict__ w, float* __restrict__ S,
                       __hip_bfloat16* __restrict__ wbf, __hip_bfloat16* __restrict__ xs) {
  int blk = blockIdx.x, tid = threadIdx.x;
  if (blk < 2048) {
    // xs_pad[b][y+1][x+1][i] = bf16(style[b,i] * x[b,i,y,x]); LDS transpose
    __shared__ float tile[64][65];
    int b = blk >> 7, rem = blk & 127, ct = rem >> 4, pt = rem & 15;
    int p0 = pt * 64, c0 = ct * 64;
    int tx = tid & 63, ty = tid >> 6;
#pragma unroll
    for (int k = 0; k < 16; ++k) {
      int ci = ty + k * 4;
      tile[ci][tx] = x[((b * 512) + (c0 + ci)) * 1024 + p0 + tx];
    }
    __syncthreads();
    float st = style[b * 512 + c0 + tx];
#pragma unroll
    for (int k = 0; k < 16; ++k) {
      int pi = ty + k * 4;
      int p = p0 + pi;
      int y = p >> 5, xx = p & 31;
      xs[(((b * 34) + (y + 1)) * 34 + (xx + 1)) * 512 + (c0 + tx)] =
          __float2bfloat16(tile[tx][pi] * st);
    }
  } else if (blk < 3072) {
    // weight -> bf16 [t][o][i], plus S[o,i] = sum_t w^2
    int idx = (blk - 2048) * 256 + tid;
    const float* p = w + idx * 9;
    float s = 0.f;
#pragma unroll
    for (int t = 0; t < 9; ++t) {
      float v = p[t];
      s += v * v;
      wbf[t * 262144 + idx] = __float2bfloat16(v);
    }
    S[idx] = s;
  } else {
    // zero padded border of xs_pad[b][34][34][512], 16B stores
    int b = blk - 3072;
    for (int i = tid; i < 8448; i += 256) {  // 132 sites * 64 chunks
      int s = i >> 6, cw = i & 63;
      int yp, xp;
      if (s < 34) { yp = 0; xp = s; }
      else if (s < 68) { yp = 33; xp = s - 34; }
      else { int t2 = s - 68; yp = 1 + (t2 >> 1); xp = (t2 & 1) * 33; }
      float4 z = {0.f, 0.f, 0.f, 0.f};
      *reinterpret_cast<float4*>(xs + (((b * 34) + yp) * 34 + xp) * 512 + cw * 8) = z;
    }
  }
}

// ---------------- K2: esc[b,o] = GAIN * rsqrt(GAIN^2 * sum_i style^2 * S + eps)
__global__ void k_sigma(const float* __restrict__ style, const float* __restrict__ S,
                        float* __restrict__ esc) {
  int gid = blockIdx.x * 4 + (threadIdx.x >> 6);
  int lane = threadIdx.x & 63;
  int b = gid >> 9, o = gid & 511;
  float s = 0.f;
#pragma unroll
  for (int j = 0; j < 8; ++j) {
    float st = style[b * 512 + j * 64 + lane];
    s += st * st * S[o * 512 + j * 64 + lane];
  }
#pragma unroll
  for (int off = 32; off; off >>= 1) s += __shfl_down(s, off);
  if (lane == 0) esc[gid] = GAINF * rsqrtf(s * (GAINF * GAINF) + EPSF);
}

// ---------------- K3: implicit-GEMM conv, 32x32x16 bf16 MFMA -----------------
// BM=128 (o) x BN=128 (4 image rows). 512 blocks x 256 thr = 2 blocks/CU.
// Double-buffered async B staging (global_load_lds) + A-frag tap pipeline.
__global__ __launch_bounds__(256, 2) void k_conv(
    const __hip_bfloat16* __restrict__ wbf, const __hip_bfloat16* __restrict__ xs,
    const float* __restrict__ esc, float* __restrict__ out) {
  __shared__ __hip_bfloat16 ldsB[2 * 6528];  // 2 bufs x 204 sites x 32 ch
  int g = blockIdx.x;
  int m = g & 3;        // fixed per XCD -> 1.18MB A slice L2-resident
  int n = g >> 2;       // 0..127 = (b, 4-row group)
  int b = n >> 3, nt = n & 7;
  int row0 = nt << 2;
  int tid = threadIdx.x;
  int lane = tid & 63, wave = tid >> 6;
  int wm = wave >> 1, wn = wave & 1;  // 2m x 2n wave grid, wave tile 64o x 64px
  int l31 = lane & 31, lhi = lane >> 5;
  int obase = (m << 7) + (wm << 6);
  const __hip_bfloat16* xbase = xs + ((b * 34 + row0) * 34) * 512;

  // precompute per-thread staging addresses (816 chunks: 204 sites x 4)
  const __hip_bfloat16* gsrc[4];
  int lofs[4];
#pragma unroll
  for (int j = 0; j < 4; ++j) {
    int idx = tid + j * 256;
    int sti = idx >> 2, q0 = idx & 3;
    int r = (sti * 241) >> 13;  // /34, exact for sti<340
    int c = sti - r * 34;
    int qs = q0 ^ ((sti >> 1) & 3);  // XOR swizzle on GLOBAL side
    gsrc[j] = xbase + ((r * 34 + c) << 9) + (qs << 3);
    lofs[j] = idx * 8;
  }
  int nch = (tid < 48) ? 4 : 3;  // 816 = 3*256 + 48

  f32x16 acc[2][2];
#pragma unroll
  for (int i = 0; i < 2; ++i)
#pragma unroll
    for (int j = 0; j < 2; ++j)
#pragma unroll
      for (int e = 0; e < 16; ++e) acc[i][j][e] = 0.f;

  // stage cb=0 into buf0 (async)
#pragma unroll
  for (int j = 0; j < 4; ++j)
    if (j < nch) GLOAD_LDS16(gsrc[j], &ldsB[lofs[j]]);

  // A-frag rotating buffers: aC/aN[k][ms]
  const __hip_bfloat16* wlane = wbf + (obase + l31) * 512 + lhi * 8;
  bf16x8 aC[2][2], aN[2][2];
#pragma unroll
  for (int k2 = 0; k2 < 2; ++k2)
#pragma unroll
    for (int ms = 0; ms < 2; ++ms)
      aC[k2][ms] = *reinterpret_cast<const bf16x8*>(wlane + ms * 16384 + k2 * 16);

  for (int cb = 0; cb < 16; ++cb) {
    __syncthreads();  // vmcnt(0) drain: stage(cb) hid under compute(cb-1)
    if (cb < 15) {    // async stage next block's channels into other buffer
      int lb = ((cb + 1) & 1) * 6528;
#pragma unroll
      for (int j = 0; j < 4; ++j)
        if (j < nch) GLOAD_LDS16(gsrc[j] + ((cb + 1) << 5), &ldsB[lb + lofs[j]]);
    }
    const __hip_bfloat16* B = &ldsB[(cb & 1) * 6528];
#pragma unroll
    for (int t = 0; t < 9; ++t) {
      // prefetch A frags for next tap (or next cb's tap 0)
      int tn = (t == 8) ? 0 : t + 1;
      int cbn = (t == 8) ? cb + 1 : cb;
      if (cbn < 16) {
        const __hip_bfloat16* wl = wlane + tn * 262144 + cbn * 32;
#pragma unroll
        for (int k2 = 0; k2 < 2; ++k2)
#pragma unroll
          for (int ms = 0; ms < 2; ++ms)
            aN[k2][ms] = *reinterpret_cast<const bf16x8*>(wl + ms * 16384 + k2 * 16);
      }
      const int dy = t / 3, dx = t - dy * 3;
      int s0 = (wn * 2 + dy) * 34 + l31 + dx;
      int s1 = s0 + 34;
#pragma unroll
      for (int k2 = 0; k2 < 2; ++k2) {
        int ko = (k2 << 1) | lhi;
        bf16x8 b0 = *reinterpret_cast<const bf16x8*>(&B[(s0 * 4 + (ko ^ ((s0 >> 1) & 3))) * 8]);
        bf16x8 b1 = *reinterpret_cast<const bf16x8*>(&B[(s1 * 4 + (ko ^ ((s1 >> 1) & 3))) * 8]);
        acc[0][0] = __builtin_amdgcn_mfma_f32_32x32x16_bf16(aC[k2][0], b0, acc[0][0], 0, 0, 0);
        acc[1][0] = __builtin_amdgcn_mfma_f32_32x32x16_bf16(aC[k2][1], b0, acc[1][0], 0, 0, 0);
        acc[0][1] = __builtin_amdgcn_mfma_f32_32x32x16_bf16(aC[k2][0], b1, acc[0][1], 0, 0, 0);
        acc[1][1] = __builtin_amdgcn_mfma_f32_32x32x16_bf16(aC[k2][1], b1, acc[1][1], 0, 0, 0);
      }
#pragma unroll
      for (int k2 = 0; k2 < 2; ++k2)
#pragma unroll
        for (int ms = 0; ms < 2; ++ms)
          aC[k2][ms] = aN[k2][ms];
    }
  }
  // epilogue: C/D layout col=lane&31, row=(reg&3)+8*(reg>>2)+4*(lane>>5)
  int pb = (row0 << 5) + (wn << 6);
#pragma unroll
  for (int ms = 0; ms < 2; ++ms)
#pragma unroll
    for (int reg = 0; reg < 16; ++reg) {
      int o = obase + ms * 32 + (reg & 3) + ((reg >> 2) << 3) + (lhi << 2);
      float e = esc[(b << 9) + o];
#pragma unroll
      for (int ns = 0; ns < 2; ++ns) {
        int p = pb + ns * 32 + l31;
        out[((b << 9) + o) * 1024 + p] = acc[ms][ns][reg] * e;
      }
    }
}

extern "C" void kernel_launch(void* const* d_in, const int* in_sizes, int n_in,
                              void* d_out, int out_size, void* d_ws, size_t ws_size,
                              hipStream_t stream) {
  const float* x = (const float*)d_in[0];      // [16,512,32,32]
  const float* style = (const float*)d_in[1];  // [16,512]
  const float* w = (const float*)d_in[2];      // [512,512,3,3]
  float* out = (float*)d_out;                  // [16,512,32,32]
  char* ws = (char*)d_ws;
  __hip_bfloat16* wbf = (__hip_bfloat16*)(ws);            // 4,718,592 B
  __hip_bfloat16* xs  = (__hip_bfloat16*)(ws + 4718592);  // 18,939,904 B
  float* S   = (float*)(ws + 23658496);                   // 1,048,576 B
  float* esc = (float*)(ws + 24707072);                   // 32,768 B

  hipLaunchKernelGGL(k_prep, dim3(3088), dim3(256), 0, stream, x, style, w, S, wbf, xs);
  hipLaunchKernelGGL(k_sigma, dim3(2048), dim3(256), 0, stream, style, S, esc);
  hipLaunchKernelGGL(k_conv, dim3(512), dim3(256), 0, stream, wbf, xs, esc, out);
}

// Round 3
// 174.130 us; speedup vs baseline: 1.4096x; 1.3578x over previous
//
#include <hip/hip_runtime.h>
#include <hip/hip_bf16.h>

#define EPSF 1e-8f
#define GAINF 0.014731391274719739f   // 1/sqrt(512*9)

typedef __attribute__((ext_vector_type(8))) __bf16 bf16x8;
typedef __attribute__((ext_vector_type(4))) __bf16 bf16x4;
typedef __attribute__((ext_vector_type(16))) float f32x16;

// async 16B global->LDS DMA; LDS dest = wave-uniform base + lane*16
#define GLOAD_LDS16(gp, lp) __builtin_amdgcn_global_load_lds( \
    (const __attribute__((address_space(1))) unsigned int*)(gp), \
    (__attribute__((address_space(3))) unsigned int*)(lp), 16, 0, 0)

// ---------------- K1 (fused): pack_x + prep_w + border zero ------------------
// xs layout: [b][cb16][site1156][32ch] bf16   (site = y*34+x, padded 34x34)
// wbf layout: [t9][cb16][o512][32ch] bf16
__global__ void k_prep(const float* __restrict__ x, const float* __restrict__ style,
                       const float* __restrict__ w, float* __restrict__ S,
                       __hip_bfloat16* __restrict__ wbf, __hip_bfloat16* __restrict__ xs) {
  int blk = blockIdx.x, tid = threadIdx.x;
  if (blk < 2048) {
    // pack: 64ch x 64px tile via LDS transpose
    __shared__ float tile[64][65];
    int b = blk >> 7, rem = blk & 127, ct = rem >> 4, pt = rem & 15;
    int p0 = pt * 64, c0 = ct * 64;
    int tx = tid & 63, ty = tid >> 6;
#pragma unroll
    for (int k = 0; k < 16; ++k) {
      int ci = ty + k * 4;
      tile[ci][tx] = x[((b * 512) + (c0 + ci)) * 1024 + p0 + tx];
    }
    __syncthreads();
    // write: thread = (ch-quad, px); 8B bf16x4 stores, 64B runs
    int tq = tid & 15, py = tid >> 4;  // tq: ch-quad 0..15, py: px 0..15
    int c = c0 + tq * 4;
    int cb = c >> 5, cw = c & 31;
    float st0 = style[b * 512 + c], st1 = style[b * 512 + c + 1];
    float st2 = style[b * 512 + c + 2], st3 = style[b * 512 + c + 3];
#pragma unroll
    for (int k = 0; k < 4; ++k) {
      int pl = py + k * 16;
      int p = p0 + pl;
      int y = p >> 5, xx = p & 31;
      int site = (y + 1) * 34 + (xx + 1);
      bf16x4 v;
      v[0] = (__bf16)(tile[tq * 4 + 0][pl] * st0);
      v[1] = (__bf16)(tile[tq * 4 + 1][pl] * st1);
      v[2] = (__bf16)(tile[tq * 4 + 2][pl] * st2);
      v[3] = (__bf16)(tile[tq * 4 + 3][pl] * st3);
      *reinterpret_cast<bf16x4*>(xs + (size_t)(((b * 16 + cb) * 1156 + site) * 32 + cw)) = v;
    }
  } else if (blk < 3072) {
    // weight -> bf16 [t][cb][o][32], plus S[o,i] = sum_t w^2
    int idx = (blk - 2048) * 256 + tid;  // o*512 + i
    int o = idx >> 9, i = idx & 511;
    const float* p = w + (size_t)idx * 9;
    float s = 0.f;
#pragma unroll
    for (int t = 0; t < 9; ++t) {
      float v = p[t];
      s += v * v;
      wbf[(size_t)t * 262144 + (i >> 5) * 16384 + o * 32 + (i & 31)] = __float2bfloat16(v);
    }
    S[idx] = s;
  } else {
    // zero border: block = (b, cb); 132 sites x 32ch
    int bb = blk - 3072;
    int b = bb >> 4, cb = bb & 15;
    for (int i2 = tid; i2 < 528; i2 += 256) {  // 132 sites x 4 chunks
      int sb = i2 >> 2, q = i2 & 3;
      int yp, xp;
      if (sb < 34) { yp = 0; xp = sb; }
      else if (sb < 68) { yp = 33; xp = sb - 34; }
      else { int t2 = sb - 68; yp = 1 + (t2 >> 1); xp = (t2 & 1) * 33; }
      float4 z = {0.f, 0.f, 0.f, 0.f};
      *reinterpret_cast<float4*>(xs + (size_t)(((b * 16 + cb) * 1156 + yp * 34 + xp) * 32 + q * 8)) = z;
    }
  }
}

// ---------------- K2: esc[b,o], S read exactly once --------------------------
__global__ void k_sigma(const float* __restrict__ style, const float* __restrict__ S,
                        float* __restrict__ esc) {
  __shared__ float s2[8192];
  __shared__ float red[4][16];
  int tid = threadIdx.x, o = blockIdx.x;
  for (int idx = tid; idx < 8192; idx += 256) {
    float v = style[idx];
    s2[idx] = v * v;
  }
  __syncthreads();
  float acc[16];
#pragma unroll
  for (int b = 0; b < 16; ++b) acc[b] = 0.f;
  for (int i = tid; i < 512; i += 256) {
    float s = S[o * 512 + i];
#pragma unroll
    for (int b = 0; b < 16; ++b) acc[b] += s2[b * 512 + i] * s;
  }
#pragma unroll
  for (int b = 0; b < 16; ++b)
#pragma unroll
    for (int off = 32; off; off >>= 1) acc[b] += __shfl_down(acc[b], off);
  int lane = tid & 63, wv = tid >> 6;
  if (lane == 0)
#pragma unroll
    for (int b = 0; b < 16; ++b) red[wv][b] = acc[b];
  __syncthreads();
  if (tid < 16) {
    float s = red[0][tid] + red[1][tid] + red[2][tid] + red[3][tid];
    esc[tid * 512 + o] = GAINF * rsqrtf(s * (GAINF * GAINF) + EPSF);
  }
}

// ---------------- K3: implicit-GEMM conv -------------------------------------
// Wave tile 64o x 128px, acc[2][4]. 64-thr blocks, grid 1024 = 4 blocks/CU,
// 1 wave/SIMD with full register file. n-pinned XCD swizzle (2 images/XCD).
__global__ __launch_bounds__(64, 1) void k_conv(
    const __hip_bfloat16* __restrict__ wbf, const __hip_bfloat16* __restrict__ xs,
    const float* __restrict__ esc, float* __restrict__ out) {
  __shared__ __hip_bfloat16 ldsB[2 * 6528];  // 2 bufs x 204 sites x 32 ch
  int g = blockIdx.x;
  int xcd = g & 7, sblk = g >> 3;
  int m = sblk >> 4;                 // 0..7 (64-o tile)
  int n = xcd * 16 + (sblk & 15);    // 0..127; each XCD owns 16 n-tiles = 2 images
  int b = n >> 3, nt = n & 7;
  int row0 = nt * 4;                 // padded rows row0..row0+5
  int lane = threadIdx.x;
  int l31 = lane & 31, lhi = lane >> 5;

  // staging offsets: 816 chunks = 12*64 + 48; XOR swizzle on global side
  int roff[13];
#pragma unroll
  for (int j = 0; j < 13; ++j) {
    int idx = lane + j * 64;
    int site = idx >> 2, q0 = idx & 3;
    int qs = q0 ^ ((site >> 1) & 3);
    roff[j] = site * 32 + qs * 8;
  }

#define STAGE(cbv) do { \
    const __hip_bfloat16* _g = xs + (size_t)((b * 16 + (cbv)) * 1156 + row0 * 34) * 32; \
    __hip_bfloat16* _l = ldsB + ((cbv) & 1) * 6528 + lane * 8; \
    _Pragma("unroll") \
    for (int _j = 0; _j < 12; ++_j) GLOAD_LDS16(_g + roff[_j], _l + _j * 512); \
    if (lane < 48) GLOAD_LDS16(_g + roff[12], _l + 12 * 512); \
  } while (0)

  int wrow = (m * 64 + l31) * 32 + lhi * 8;
#define LOADA(dst, t_, cb_) do { \
    const __hip_bfloat16* _p = wbf + (size_t)(t_) * 262144 + (cb_) * 16384 + wrow; \
    dst[0][0] = *reinterpret_cast<const bf16x8*>(_p); \
    dst[0][1] = *reinterpret_cast<const bf16x8*>(_p + 1024); \
    dst[1][0] = *reinterpret_cast<const bf16x8*>(_p + 16); \
    dst[1][1] = *reinterpret_cast<const bf16x8*>(_p + 1024 + 16); \
  } while (0)

  f32x16 acc[2][4];
#pragma unroll
  for (int i = 0; i < 2; ++i)
#pragma unroll
    for (int j = 0; j < 4; ++j)
#pragma unroll
      for (int e = 0; e < 16; ++e) acc[i][j][e] = 0.f;

  bf16x8 aC[2][2], aN[2][2];  // [k2][ms]
  STAGE(0);
  LOADA(aC, 0, 0);

  for (int cb = 0; cb < 16; ++cb) {
    __syncthreads();              // drains stage(cb) (issued one full cb ago)
    if (cb < 15) STAGE(cb + 1);   // async into other buffer, in flight all cb
    const __hip_bfloat16* lb = ldsB + (cb & 1) * 6528;
#pragma unroll
    for (int t = 0; t < 9; ++t) {
      const int dy = t / 3, dx = t - dy * 3;
      if (cb < 15 || t < 8) {     // prefetch next tap's A (1 tap = 16 MFMAs ahead)
        int tn = (t == 8) ? 0 : t + 1;
        int cbn = (t == 8) ? cb + 1 : cb;
        LOADA(aN, tn, cbn);
      }
      int s[4], sw[4];
#pragma unroll
      for (int ns = 0; ns < 4; ++ns) {
        s[ns] = (ns + dy) * 34 + l31 + dx;
        sw[ns] = (s[ns] >> 1) & 3;
      }
#pragma unroll
      for (int k2 = 0; k2 < 2; ++k2) {
        int ko = (k2 << 1) | lhi;
        bf16x8 bf[4];
#pragma unroll
        for (int ns = 0; ns < 4; ++ns)
          bf[ns] = *reinterpret_cast<const bf16x8*>(&lb[(s[ns] * 4 + (ko ^ sw[ns])) * 8]);
#pragma unroll
        for (int ns = 0; ns < 4; ++ns) {
          acc[0][ns] = __builtin_amdgcn_mfma_f32_32x32x16_bf16(aC[k2][0], bf[ns], acc[0][ns], 0, 0, 0);
          acc[1][ns] = __builtin_amdgcn_mfma_f32_32x32x16_bf16(aC[k2][1], bf[ns], acc[1][ns], 0, 0, 0);
        }
      }
#pragma unroll
      for (int k2 = 0; k2 < 2; ++k2)
#pragma unroll
        for (int ms = 0; ms < 2; ++ms)
          aC[k2][ms] = aN[k2][ms];
    }
  }
  // epilogue: C/D layout col=lane&31, row=(reg&3)+8*(reg>>2)+4*(lane>>5)
  int pxb = nt * 128 + l31;
#pragma unroll
  for (int ms = 0; ms < 2; ++ms)
#pragma unroll
    for (int reg = 0; reg < 16; ++reg) {
      int o = m * 64 + ms * 32 + (reg & 3) + ((reg >> 2) << 3) + (lhi << 2);
      float e = esc[(b << 9) + o];
#pragma unroll
      for (int ns = 0; ns < 4; ++ns)
        out[(size_t)((b << 9) + o) * 1024 + pxb + ns * 32] = acc[ms][ns][reg] * e;
    }
#undef STAGE
#undef LOADA
}

extern "C" void kernel_launch(void* const* d_in, const int* in_sizes, int n_in,
                              void* d_out, int out_size, void* d_ws, size_t ws_size,
                              hipStream_t stream) {
  const float* x = (const float*)d_in[0];      // [16,512,32,32]
  const float* style = (const float*)d_in[1];  // [16,512]
  const float* w = (const float*)d_in[2];      // [512,512,3,3]
  float* out = (float*)d_out;                  // [16,512,32,32]
  char* ws = (char*)d_ws;
  __hip_bfloat16* wbf = (__hip_bfloat16*)(ws);            // 9*16*512*32*2 = 4,718,592
  __hip_bfloat16* xs  = (__hip_bfloat16*)(ws + 4718592);  // 16*16*1156*32*2 = 18,939,904
  float* S   = (float*)(ws + 23658496);                   // 1,048,576
  float* esc = (float*)(ws + 24707072);                   // 32,768

  hipLaunchKernelGGL(k_prep, dim3(3328), dim3(256), 0, stream, x, style, w, S, wbf, xs);
  hipLaunchKernelGGL(k_sigma, dim3(512), dim3(256), 0, stream, style, S, esc);
  hipLaunchKernelGGL(k_conv, dim3(1024), dim3(64), 0, stream, wbf, xs, esc, out);
}